// Round 11
// baseline (248.097 us; speedup 1.0000x reference)
//
#include <hip/hip_runtime.h>

// Problem constants (from reference)
#define CC 9605
#define BB 2048
#define LL 8
#define CAND_MAX 384
#define NEGF (-1e30f)
#define NINF (-__builtin_huge_valf())
#define LOMIN 0x00800000u  // enc(-FLT_MAX): lowest threshold decoding to a finite float

// d_ws layout:
//   wsu[0] = wl entry count (atomic); wsu[1] = sniff flags
//   wsu[4 .. 4+2048) = whitelist entries (col<<8 | mask)
//   byte 16384: float partials[BB]
//   byte 24576: unsigned rowmax_enc[BB]
#define WS_PARTIALS_OFF 16384
#define WS_ROWMAX_OFF 24576

__device__ __forceinline__ unsigned enc_f(float f) {
  unsigned u = __float_as_uint(f);
  return (u & 0x80000000u) ? ~u : (u | 0x80000000u);
}
__device__ __forceinline__ float dec_u(unsigned e) {
  unsigned u = (e & 0x80000000u) ? (e & 0x7fffffffu) : ~e;
  return __uint_as_float(u);
}
__device__ __forceinline__ float sigm(float z) {
  return 1.0f / (1.0f + __expf(-z));
}

// ---- dtype sniff: byte signatures over the raw wl buffer ----
__global__ void wl_sniff(const unsigned* __restrict__ wlw,
                         unsigned* __restrict__ wsu) {
  const int nwords = (LL * CC) / 4;
  const int stride = gridDim.x * blockDim.x;
  unsigned f = 0u;
  for (int j = blockIdx.x * blockDim.x + threadIdx.x; j < nwords; j += stride) {
    unsigned w = wlw[j];
#pragma unroll
    for (int k = 0; k < 4; ++k) {
      unsigned b = (w >> (8 * k)) & 255u;
      if (b == 1u)    { f |= 2u; if (k != 0) f |= 1u; }
      if (b == 0x3fu) { f |= 8u; if (k == 1) f |= 4u; }
    }
  }
#pragma unroll
  for (int off = 32; off >= 1; off >>= 1) f |= __shfl_xor(f, off, 64);
  if ((threadIdx.x & 63) == 0 && f) atomicOr(&wsu[1], f);
}

__global__ void wl_compact(const unsigned char* __restrict__ wl,
                           unsigned* __restrict__ wsu) {
  const int tid = threadIdx.x;
  const int lane = tid & 63;
  const int c = blockIdx.x * 256 + tid;
  const unsigned g = wsu[1];
  const int dt = (g & 1u) ? 0 : (g & 4u) ? 3 : (g & 2u) ? 1 : (g & 8u) ? 2 : 0;
  const int* wl32 = (const int*)wl;
  const float* wlf = (const float*)wl;
  const unsigned short* wlh = (const unsigned short*)wl;
  unsigned m = 0u;
  if (c < CC) {
#pragma unroll
    for (int l = 0; l < LL; ++l) {
      int j = l * CC + c;
      bool on;
      if (dt == 0) on = (wl[j] != 0);
      else if (dt == 1) on = (wl32[j] != 0);
      else if (dt == 2) on = (wlf[j] != 0.0f);
      else on = (wlh[j] != 0);
      if (on) m |= (1u << l);
    }
  }
  unsigned long long bal = __ballot(m != 0u);
  if (bal) {
    unsigned wcnt = (unsigned)__popcll(bal);
    unsigned basep = 0u;
    if (lane == 0) basep = atomicAdd(&wsu[0], wcnt);
    basep = __shfl(basep, 0, 64);
    if (m) {
      unsigned pos = basep + (unsigned)__popcll(bal & ((1ull << lane) - 1ull));
      if (pos < 2048u) wsu[4 + pos] = ((unsigned)c << 8) | m;
    }
  }
}

// ---------------------------------------------------------------------------
// PASS A: per-row max, minimal VALU (1 fmax/value). Rounds are pure memory
// latency (VALU << 900cy), so 8192 waves x 1KB outstanding saturate HBM by
// Little's law. This is the falsifier for the session theory: R9's identical
// load structure sat at 1.5 TB/s ONLY because 176+cy of top-11 insert VALU
// per round throttled the issue rate (VALUBusy showed 3.5x my hand count --
// the sorted-register insert chain inflates to ~4 inst/stage).
// ---------------------------------------------------------------------------
__global__ __launch_bounds__(256) void rowmax_kernel(
    const float* __restrict__ x, unsigned* __restrict__ rowmax) {
  __shared__ float shm[4];
  const int tid = threadIdx.x, lane = tid & 63, wid = tid >> 6;
  const int r = blockIdx.x;
  const long long base = (long long)r * CC;
  const int soff = (4 - (r & 3)) & 3;
  const int ng = (CC - soff) >> 2;          // 2400 or 2401
  const int tailn = CC - soff - (ng << 2);
  const int m_extra = soff + tailn;         // <= 5 scalars
  const float4* vp = (const float4*)(x + base + soff);
  float m = NINF;
#pragma unroll
  for (int k = 0; k < 9; ++k) {             // max idx 2303 < 2400 <= ng
    float4 t = vp[tid + (k << 8)];
    m = fmaxf(m, fmaxf(fmaxf(t.x, t.y), fmaxf(t.z, t.w)));
  }
  {
    int gi = tid + 2304;
    if (gi < ng) {
      float4 t = vp[gi];
      m = fmaxf(m, fmaxf(fmaxf(t.x, t.y), fmaxf(t.z, t.w)));
    }
  }
  if (tid < m_extra) {
    int tc = (tid < soff) ? tid : (soff + (ng << 2) + (tid - soff));
    m = fmaxf(m, x[base + tc]);
  }
#pragma unroll
  for (int off = 32; off >= 1; off >>= 1) m = fmaxf(m, __shfl_xor(m, off, 64));
  if (lane == 0) shm[wid] = m;
  __syncthreads();
  if (tid == 0)
    rowmax[r] = enc_f(fmaxf(fmaxf(shm[0], shm[1]), fmaxf(shm[2], shm[3])));
}

// ---------------------------------------------------------------------------
// PASS B: x is L3-resident (78.7MB < 256MB) after pass A. Per row: fused
// count+compact stream at T = enc_max - 2^22 (expected ~22 candidates for
// N(0,2)); exact select via wave-0 ballot binary search. Widen (c<11) and
// bisect (c>384) re-passes are L3-cheap and astronomically rare for the
// bench distribution, but keep the result exact for ALL inputs.
// Per value: 1 float cmp + rare append -- no sorted-register chains.
// Float-vs-encoded compare is superset-safe (only +-0 aliasing, and +-0
// ties produce identical loss: sigm(+-0)=0.5).
// ---------------------------------------------------------------------------

#define FOR8(OP) OP(0) OP(1) OP(2) OP(3) OP(4) OP(5) OP(6) OP(7)

#define APPEND1(V, PRED)                                                     \
  {                                                                          \
    bool _p = (PRED);                                                        \
    unsigned long long _bal = __ballot(_p);                                  \
    if (_bal) {                                                              \
      unsigned _wt = (unsigned)__popcll(_bal);                               \
      unsigned _bp = 0u;                                                     \
      if (lane == 0) _bp = atomicAdd(&sh_cnt, _wt);                          \
      _bp = __shfl(_bp, 0, 64);                                              \
      if (_p) {                                                              \
        unsigned _pos =                                                      \
            _bp + (unsigned)__popcll(_bal & ((1ull << lane) - 1ull));        \
        if (_pos < CAND_MAX) sh_cand[_pos] = enc_f(V);                       \
      }                                                                      \
    }                                                                        \
  }

#define COMPACT_PASS(TENC, RES)                                              \
  do {                                                                       \
    float Tf = dec_u(TENC);                                                  \
    __syncthreads();                                                         \
    if (tid == 0) sh_cnt = 0u;                                               \
    __syncthreads();                                                         \
    _Pragma("unroll") for (int k = 0; k < 9; ++k) {                          \
      float4 t = vp[tid + (k << 8)];                                         \
      APPEND1(t.x, t.x >= Tf) APPEND1(t.y, t.y >= Tf)                        \
      APPEND1(t.z, t.z >= Tf) APPEND1(t.w, t.w >= Tf)                        \
    }                                                                        \
    {                                                                        \
      float4 t = make_float4(NINF, NINF, NINF, NINF);                        \
      if (tid + 2304 < ng) t = vp[tid + 2304];                               \
      APPEND1(t.x, t.x >= Tf) APPEND1(t.y, t.y >= Tf)                        \
      APPEND1(t.z, t.z >= Tf) APPEND1(t.w, t.w >= Tf)                        \
    }                                                                        \
    APPEND1(tailv, tailv >= Tf)                                              \
    __syncthreads();                                                         \
    RES = sh_cnt;                                                            \
  } while (0)

#define COUNT_PASS(TENC, RES)                                                \
  do {                                                                       \
    float Tf = dec_u(TENC);                                                  \
    unsigned cl = 0u;                                                        \
    _Pragma("unroll") for (int k = 0; k < 9; ++k) {                          \
      float4 t = vp[tid + (k << 8)];                                         \
      cl += (t.x >= Tf) + (t.y >= Tf) + (t.z >= Tf) + (t.w >= Tf);           \
    }                                                                        \
    {                                                                        \
      float4 t = make_float4(NINF, NINF, NINF, NINF);                        \
      if (tid + 2304 < ng) t = vp[tid + 2304];                               \
      cl += (t.x >= Tf) + (t.y >= Tf) + (t.z >= Tf) + (t.w >= Tf);           \
    }                                                                        \
    cl += (tailv >= Tf) ? 1u : 0u;                                           \
    _Pragma("unroll") for (int off = 32; off >= 1; off >>= 1)                \
        cl += __shfl_xor(cl, off, 64);                                       \
    __syncthreads();                                                         \
    if (lane == 0) sh_redC[wid] = cl;                                        \
    __syncthreads();                                                         \
    RES = sh_redC[0] + sh_redC[1] + sh_redC[2] + sh_redC[3];                 \
  } while (0)

__global__ __launch_bounds__(256) void loss_kernel(
    const float* __restrict__ x, const float* __restrict__ y,
    const unsigned* __restrict__ wsu, const unsigned* __restrict__ rowmax,
    float* __restrict__ partials) {
  __shared__ unsigned sh_cand[CAND_MAX];
  __shared__ unsigned sh_redC[4];
  __shared__ unsigned sh_cnt;
  __shared__ float sh_wlm[4][8];
  __shared__ unsigned sh_wpm[4];

  const int tid = threadIdx.x, lane = tid & 63, wid = tid >> 6;
  const int r = blockIdx.x;
  const long long base = (long long)r * CC;
  const int soff = (4 - (r & 3)) & 3;
  const int ng = (CC - soff) >> 2;
  const int tailn = CC - soff - (ng << 2);
  const int m_extra = soff + tailn;
  const float4* vp = (const float4*)(x + base + soff);
  float tailv = NINF;
  if (tid < m_extra) {
    int tc = (tid < soff) ? tid : (soff + (ng << 2) + (tid - soff));
    tailv = x[base + tc];
  }
  const unsigned Emax = rowmax[r];
  const unsigned nu = min(wsu[0], 2048u);
  const unsigned* ents = wsu + 4;

  // ---- threshold probe: expected ONE fused count+compact pass ----
  unsigned lo = (Emax > LOMIN + (1u << 22)) ? Emax - (1u << 22) : LOMIN;
  unsigned hi = Emax + 1u;
  unsigned c;
  bool done = false;
  unsigned E11 = 0u;
  COMPACT_PASS(lo, c);
  unsigned compLo = lo;
  while (c < 11u && lo > LOMIN) {            // widen (rare)
    hi = lo;
    lo = (lo > LOMIN + (1u << 23)) ? lo - (1u << 23) : LOMIN;
    COMPACT_PASS(lo, c);
    compLo = lo;
  }
  if (c < 11u) { E11 = LOMIN; done = true; } // 11th < -FLT_MAX -> thres 0.5
  while (!done && c > CAND_MAX) {            // bisect (rare)
    if (hi - lo <= 1u) { E11 = lo; done = true; break; }
    unsigned mid = lo + ((hi - lo) >> 1);
    unsigned cm;
    COUNT_PASS(mid, cm);
    if (cm >= 11u) { lo = mid; c = cm; } else { hi = mid; }
  }
  if (!done && lo != compLo) { COMPACT_PASS(lo, c); }

  // ---- whitelist fold (L3/L2-hot gathers), all waves ----
  unsigned en0 = ((unsigned)tid < nu) ? ents[tid] : 0u;
  unsigned en1 = ((unsigned)tid + 256u < nu) ? ents[tid + 256] : 0u;
  float gx0 = x[base + (en0 >> 8)], gy0 = y[base + (en0 >> 8)];
  float gx1 = x[base + (en1 >> 8)], gy1 = y[base + (en1 >> 8)];
#define DECL_LM(k) float lm_##k = NEGF;
  FOR8(DECL_LM)
  unsigned pmask = 0u;
#define FOLDE(EN, GX, GY)                                        \
  {                                                              \
    unsigned mk = (EN) & 255u;                                   \
    pmask |= mk;                                                 \
    if ((GY) > 0.0f) pmask |= (mk << 8);                         \
    if (mk & 1u)   lm_0 = fmaxf(lm_0, (GX));                     \
    if (mk & 2u)   lm_1 = fmaxf(lm_1, (GX));                     \
    if (mk & 4u)   lm_2 = fmaxf(lm_2, (GX));                     \
    if (mk & 8u)   lm_3 = fmaxf(lm_3, (GX));                     \
    if (mk & 16u)  lm_4 = fmaxf(lm_4, (GX));                     \
    if (mk & 32u)  lm_5 = fmaxf(lm_5, (GX));                     \
    if (mk & 64u)  lm_6 = fmaxf(lm_6, (GX));                     \
    if (mk & 128u) lm_7 = fmaxf(lm_7, (GX));                     \
  }
  FOLDE(en0, gx0, gy0)
  FOLDE(en1, gx1, gy1)
  for (unsigned e = 512u + (unsigned)tid; e < nu; e += 256u) {  // safety net
    unsigned ent = ents[e];
    float xv = x[base + (ent >> 8)];
    float yv = y[base + (ent >> 8)];
    FOLDE(ent, xv, yv)
  }
#pragma unroll
  for (int off = 32; off >= 1; off >>= 1) {
    pmask |= __shfl_xor(pmask, off, 64);
#define RED1(l) lm_##l = fmaxf(lm_##l, __shfl_xor(lm_##l, off, 64));
    FOR8(RED1)
#undef RED1
  }
  if (lane == 0) {
#define STL(l) sh_wlm[wid][l] = lm_##l;
    FOR8(STL)
#undef STL
    sh_wpm[wid] = pmask;
  }
  __syncthreads();
  if (wid != 0) return;

  // ---- wave 0: exact 11th-largest via value binary search over cands ----
  if (!done) {
    unsigned c0 = ((unsigned)lane < c) ? sh_cand[lane] : 0u;
    unsigned c1 = ((unsigned)lane + 64u < c) ? sh_cand[lane + 64u] : 0u;
    unsigned c2 = ((unsigned)lane + 128u < c) ? sh_cand[lane + 128u] : 0u;
    unsigned c3 = ((unsigned)lane + 192u < c) ? sh_cand[lane + 192u] : 0u;
    unsigned c4 = ((unsigned)lane + 256u < c) ? sh_cand[lane + 256u] : 0u;
    unsigned c5 = ((unsigned)lane + 320u < c) ? sh_cand[lane + 320u] : 0u;
    unsigned blo = lo, bhi = hi;
    while (bhi - blo > 1u) {                 // <= ~24 iters, ballots only
      unsigned mid = blo + ((bhi - blo) >> 1);
      unsigned cnt = (unsigned)__popcll(__ballot(c0 >= mid)) +
                     (unsigned)__popcll(__ballot(c1 >= mid)) +
                     (unsigned)__popcll(__ballot(c2 >= mid)) +
                     (unsigned)__popcll(__ballot(c3 >= mid)) +
                     (unsigned)__popcll(__ballot(c4 >= mid)) +
                     (unsigned)__popcll(__ballot(c5 >= mid));
      if (cnt >= 11u) blo = mid; else bhi = mid;
    }
    E11 = blo;
  }

  // ---- lane 0: combine whitelist partials, per-row loss ----
  if (lane == 0) {
#pragma unroll
    for (int j = 1; j < 4; ++j) {
      pmask |= sh_wpm[j];
#define CMB(l) lm_##l = fmaxf(lm_##l, sh_wlm[j][l]);
      FOR8(CMB)
#undef CMB
    }
    unsigned PR = pmask & 255u, PO = (pmask >> 8) & 255u;
    float thres = fmaxf(sigm(dec_u(E11)), 0.5f);
    float cmax = NEGF, imax = NEGF, umax = NEGF;
#define EP1(l)                                                   \
    if ((PR >> l) & 1u) {                                        \
      float ml = sigm(lm_##l);                                   \
      umax = fmaxf(umax, ml);                                    \
      if ((PO >> l) & 1u) cmax = fmaxf(cmax, ml);                \
      else imax = fmaxf(imax, ml);                               \
    }
    FOR8(EP1)
#undef EP1
    bool anyc = (PO != 0u);
    bool anyi = (PO != 255u);  // L == 8 labels always exist
    float x1 = anyc ? cmax : thres;
    float x2 = anyc ? (anyi ? fmaxf(imax, thres) : thres)
                    : ((nu > 0u) ? umax : NEGF);
    float coef = anyc ? 1.0f : 0.5f;
    float dd = x2 - x1 + 0.1f;
    float rank = ((dd > 0.0f) ? 2.0f : 1.0f) * sigm(10.0f * dd);
    partials[r] = coef * rank;
  }
}

__global__ void final_reduce(const float* __restrict__ partials,
                             float* __restrict__ out) {
  __shared__ float sh[4];
  const int tid = threadIdx.x;
  const int lane = tid & 63;
  const int wid = tid >> 6;
  float s = 0.0f;
  for (int i = tid; i < BB; i += 256) s += partials[i];
#pragma unroll
  for (int off = 32; off >= 1; off >>= 1) s += __shfl_xor(s, off, 64);
  if (lane == 0) sh[wid] = s;
  __syncthreads();
  if (tid == 0) out[0] = (sh[0] + sh[1] + sh[2] + sh[3]) * (1.0f / (float)BB);
}

extern "C" void kernel_launch(void* const* d_in, const int* in_sizes, int n_in,
                              void* d_out, int out_size, void* d_ws,
                              size_t ws_size, hipStream_t stream) {
  const float* x = (const float*)d_in[0];
  const float* y = (const float*)d_in[1];
  // d_in[2] (y_neg) is faithfully ignored — it never affects the loss.
  const unsigned char* wl = (const unsigned char*)d_in[3];
  float* out = (float*)d_out;
  unsigned* wsu = (unsigned*)d_ws;
  float* partials = (float*)((char*)d_ws + WS_PARTIALS_OFF);
  unsigned* rowmax = (unsigned*)((char*)d_ws + WS_ROWMAX_OFF);

  hipMemsetAsync(d_ws, 0, 16, stream);  // zero wsu[0..3]
  wl_sniff<<<64, 256, 0, stream>>>((const unsigned*)wl, wsu);
  wl_compact<<<(CC + 255) / 256, 256, 0, stream>>>(wl, wsu);
  rowmax_kernel<<<BB, 256, 0, stream>>>(x, rowmax);
  loss_kernel<<<BB, 256, 0, stream>>>(x, y, wsu, rowmax, partials);
  final_reduce<<<1, 256, 0, stream>>>(partials, out);
}

// Round 12
// 228.821 us; speedup vs baseline: 1.0842x; 1.0842x over previous
//
#include <hip/hip_runtime.h>

// Problem constants (from reference)
#define CC 9605
#define BB 2048
#define LL 8
#define CAND_MAX 384
#define NEGF (-1e30f)
#define NINF (-__builtin_huge_valf())
#define LOMIN 0x00800000u  // enc(-FLT_MAX)

// d_ws layout:
//   wsu[0] = wl entry count (atomic); wsu[1] = sniff flags
//   wsu[4 .. 4+2048) = whitelist entries (col<<8 | mask)
//   byte 16384: float partials[BB]
#define WS_PARTIALS_OFF 16384

__device__ __forceinline__ unsigned enc_f(float f) {
  unsigned u = __float_as_uint(f);
  return (u & 0x80000000u) ? ~u : (u | 0x80000000u);
}
__device__ __forceinline__ float dec_u(unsigned e) {
  unsigned u = (e & 0x80000000u) ? (e & 0x7fffffffu) : ~e;
  return __uint_as_float(u);
}
__device__ __forceinline__ float sigm(float z) {
  return 1.0f / (1.0f + __expf(-z));
}

// ---- dtype sniff: byte signatures over the raw wl buffer ----
__global__ void wl_sniff(const unsigned* __restrict__ wlw,
                         unsigned* __restrict__ wsu) {
  const int nwords = (LL * CC) / 4;
  const int stride = gridDim.x * blockDim.x;
  unsigned f = 0u;
  for (int j = blockIdx.x * blockDim.x + threadIdx.x; j < nwords; j += stride) {
    unsigned w = wlw[j];
#pragma unroll
    for (int k = 0; k < 4; ++k) {
      unsigned b = (w >> (8 * k)) & 255u;
      if (b == 1u)    { f |= 2u; if (k != 0) f |= 1u; }
      if (b == 0x3fu) { f |= 8u; if (k == 1) f |= 4u; }
    }
  }
#pragma unroll
  for (int off = 32; off >= 1; off >>= 1) f |= __shfl_xor(f, off, 64);
  if ((threadIdx.x & 63) == 0 && f) atomicOr(&wsu[1], f);
}

__global__ void wl_compact(const unsigned char* __restrict__ wl,
                           unsigned* __restrict__ wsu) {
  const int tid = threadIdx.x;
  const int lane = tid & 63;
  const int c = blockIdx.x * 256 + tid;
  const unsigned g = wsu[1];
  const int dt = (g & 1u) ? 0 : (g & 4u) ? 3 : (g & 2u) ? 1 : (g & 8u) ? 2 : 0;
  const int* wl32 = (const int*)wl;
  const float* wlf = (const float*)wl;
  const unsigned short* wlh = (const unsigned short*)wl;
  unsigned m = 0u;
  if (c < CC) {
#pragma unroll
    for (int l = 0; l < LL; ++l) {
      int j = l * CC + c;
      bool on;
      if (dt == 0) on = (wl[j] != 0);
      else if (dt == 1) on = (wl32[j] != 0);
      else if (dt == 2) on = (wlf[j] != 0.0f);
      else on = (wlh[j] != 0);
      if (on) m |= (1u << l);
    }
  }
  unsigned long long bal = __ballot(m != 0u);
  if (bal) {
    unsigned wcnt = (unsigned)__popcll(bal);
    unsigned basep = 0u;
    if (lane == 0) basep = atomicAdd(&wsu[0], wcnt);
    basep = __shfl(basep, 0, 64);
    if (m) {
      unsigned pos = basep + (unsigned)__popcll(bal & ((1ull << lane) - 1ull));
      if (pos < 2048u) wsu[4 + pos] = ((unsigned)c << 8) | m;
    }
  }
}

// ---------------------------------------------------------------------------
// FUSED: 6TB/s max-stream + chunk-max sketch + wave-0 L2 rescan.
// R11 proved: (a) the pure-fmax stream runs at ~6 TB/s / 13us (rowmax pass);
// (b) any per-value selection work interleaved with the stream throttles it
// 4x; (c) a second full pass re-fetches (FETCH 84MB). So: stream once with
// ONLY fmax per value; each thread's private max IS a free 256-entry
// chunk-max sketch. Exactness: let cm11 = 11th-largest chunk max. The >=11
// chunks with max >= cm11 give >=11 distinct values >= cm11 => v11 >= cm11;
// every value >= v11 lies in a chunk with max >= v11 >= cm11 (a candidate
// chunk). So rescanning only candidate chunks (~11 x 38 = ~420 values, L2-
// hot) is exact. Wave 0 does the whole tail alone (no barriers after the
// single one); waves 1-3 exit after publishing whitelist partials.
// ---------------------------------------------------------------------------

#define FOR8(OP) OP(0) OP(1) OP(2) OP(3) OP(4) OP(5) OP(6) OP(7)

// wave-0 append with uniform register base (no atomics, no shfl)
#define WAPPEND(V, P)                                                        \
  {                                                                          \
    bool _p = (P);                                                           \
    unsigned long long _bal = __ballot(_p);                                  \
    if (_p) {                                                                \
      unsigned _pos =                                                        \
          cnt + (unsigned)__popcll(_bal & ((1ull << lane) - 1ull));          \
      if (_pos < CAND_MAX) sh_cand[_pos] = enc_f(V);                         \
    }                                                                        \
    cnt += (unsigned)__popcll(_bal);                                         \
  }

__global__ __launch_bounds__(256) void loss_kernel(
    const float* __restrict__ x, const float* __restrict__ y,
    const unsigned* __restrict__ wsu, float* __restrict__ partials) {
  __shared__ float sh_pm[256];         // per-thread (chunk) maxes
  __shared__ unsigned sh_list[256];    // candidate chunk ids
  __shared__ unsigned sh_cand[CAND_MAX];
  __shared__ float sh_wlm[4][8];
  __shared__ unsigned sh_wpm[4];

  const int tid = threadIdx.x, lane = tid & 63, wid = tid >> 6;
  const int r = blockIdx.x;
  const long long base = (long long)r * CC;
  const int soff = (4 - (r & 3)) & 3;
  const int ng = (CC - soff) >> 2;          // 2400 or 2401
  const int tailn = CC - soff - (ng << 2);
  const int m_extra = soff + tailn;         // <= 5 scalars
  const float4* vp = (const float4*)(x + base + soff);

  // ---- 1. stream: ONLY fmax per value (the proven 6TB/s shape) ----
  float m = NINF;
#pragma unroll
  for (int k = 0; k < 9; ++k) {             // max idx 2303 < 2400 <= ng
    float4 t = vp[tid + (k << 8)];
    m = fmaxf(m, fmaxf(fmaxf(t.x, t.y), fmaxf(t.z, t.w)));
  }
  {
    int gi = tid + 2304;
    if (gi < ng) {
      float4 t = vp[gi];
      m = fmaxf(m, fmaxf(fmaxf(t.x, t.y), fmaxf(t.z, t.w)));
    }
  }
  if (tid < m_extra) {
    int tc = (tid < soff) ? tid : (soff + (ng << 2) + (tid - soff));
    m = fmaxf(m, x[base + tc]);
  }
  sh_pm[tid] = m;

  // ---- 2. whitelist fold (all waves; gathers overlap the stream drain) ----
  const unsigned nu = min(wsu[0], 2048u);
  const unsigned* ents = wsu + 4;
  unsigned en0 = ((unsigned)tid < nu) ? ents[tid] : 0u;
  unsigned en1 = ((unsigned)tid + 256u < nu) ? ents[tid + 256] : 0u;
  float gx0 = x[base + (en0 >> 8)], gy0 = y[base + (en0 >> 8)];
  float gx1 = x[base + (en1 >> 8)], gy1 = y[base + (en1 >> 8)];
#define DECL_LM(k) float lm_##k = NEGF;
  FOR8(DECL_LM)
  unsigned pmask = 0u;
#define FOLDE(EN, GX, GY)                                        \
  {                                                              \
    unsigned mk = (EN) & 255u;                                   \
    pmask |= mk;                                                 \
    if ((GY) > 0.0f) pmask |= (mk << 8);                         \
    if (mk & 1u)   lm_0 = fmaxf(lm_0, (GX));                     \
    if (mk & 2u)   lm_1 = fmaxf(lm_1, (GX));                     \
    if (mk & 4u)   lm_2 = fmaxf(lm_2, (GX));                     \
    if (mk & 8u)   lm_3 = fmaxf(lm_3, (GX));                     \
    if (mk & 16u)  lm_4 = fmaxf(lm_4, (GX));                     \
    if (mk & 32u)  lm_5 = fmaxf(lm_5, (GX));                     \
    if (mk & 64u)  lm_6 = fmaxf(lm_6, (GX));                     \
    if (mk & 128u) lm_7 = fmaxf(lm_7, (GX));                     \
  }
  FOLDE(en0, gx0, gy0)
  FOLDE(en1, gx1, gy1)
  for (unsigned e = 512u + (unsigned)tid; e < nu; e += 256u) {  // safety net
    unsigned ent = ents[e];
    float xv = x[base + (ent >> 8)];
    float yv = y[base + (ent >> 8)];
    FOLDE(ent, xv, yv)
  }
#pragma unroll
  for (int off = 32; off >= 1; off >>= 1) {
    pmask |= __shfl_xor(pmask, off, 64);
#define RED1(l) lm_##l = fmaxf(lm_##l, __shfl_xor(lm_##l, off, 64));
    FOR8(RED1)
#undef RED1
  }
  if (lane == 0) {
#define STL(l) sh_wlm[wid][l] = lm_##l;
    FOR8(STL)
#undef STL
    sh_wpm[wid] = pmask;
  }

  __syncthreads();   // the ONLY barrier; after it waves 1-3 are done
  if (wid != 0) return;

  // ---- 3. wave 0: ecm11 = exact 11th-largest chunk max (registers) ----
  unsigned ep0 = enc_f(sh_pm[lane]);
  unsigned ep1 = enc_f(sh_pm[lane + 64]);
  unsigned ep2 = enc_f(sh_pm[lane + 128]);
  unsigned ep3 = enc_f(sh_pm[lane + 192]);
  unsigned eEmax = max(max(ep0, ep1), max(ep2, ep3));
#pragma unroll
  for (int off = 32; off >= 1; off >>= 1)
    eEmax = max(eEmax, __shfl_xor(eEmax, off, 64));
  unsigned lo = min(LOMIN, eEmax), hi = eEmax + 1u;
  while (hi - lo > 1u) {                    // <= 32 iters, ballots only
    unsigned mid = lo + ((hi - lo) >> 1);
    unsigned c4 = ((ep0 >= mid) ? 1u : 0u) + ((ep1 >= mid) ? 1u : 0u) +
                  ((ep2 >= mid) ? 1u : 0u) + ((ep3 >= mid) ? 1u : 0u);
    unsigned tot = (unsigned)__popcll(__ballot(c4 & 1u)) +
                   ((unsigned)__popcll(__ballot(c4 & 2u)) << 1) +
                   ((unsigned)__popcll(__ballot(c4 & 4u)) << 2);
    if (tot >= 11u) lo = mid; else hi = mid;
  }
  const unsigned ecm11 = lo;
  hi = eEmax + 1u;                          // reset hi for the value search

  // ---- 4. candidate chunk list (ids of chunks with max >= cm11) ----
  unsigned ncc = 0u;
#define LISTJ(EP, J)                                                         \
  {                                                                          \
    bool _p = ((EP) >= ecm11);                                               \
    unsigned long long _bal = __ballot(_p);                                  \
    if (_p) sh_list[ncc + (unsigned)__popcll(_bal & ((1ull << lane) - 1ull))] \
        = (unsigned)(lane + 64 * (J));                                       \
    ncc += (unsigned)__popcll(_bal);                                         \
  }
  LISTJ(ep0, 0) LISTJ(ep1, 1) LISTJ(ep2, 2) LISTJ(ep3, 3)
#undef LISTJ

  // ---- 5. compact candidate-chunk values >= T into sh_cand (L2-hot) ----
#define CAND_COMPACT(TENC, RES)                                              \
  do {                                                                       \
    float Tf = dec_u(TENC);                                                  \
    unsigned cnt = 0u;                                                       \
    for (unsigned i0 = 0; i0 < ncc; i0 += 64u) {  /* uniform trip */         \
      unsigned i = i0 + (unsigned)lane;                                      \
      bool have = (i < ncc);                                                 \
      int cch = have ? (int)sh_list[i] : 0;                                  \
      for (int j = 0; j < 10; ++j) {                                         \
        bool ok = have && ((j < 9) || (cch + 2304 < ng));                    \
        float4 t = make_float4(NINF, NINF, NINF, NINF);                      \
        if (ok) t = vp[cch + (j << 8)];                                      \
        WAPPEND(t.x, t.x >= Tf) WAPPEND(t.y, t.y >= Tf)                      \
        WAPPEND(t.z, t.z >= Tf) WAPPEND(t.w, t.w >= Tf)                      \
      }                                                                      \
      float tv = NINF;                                                       \
      if (have && cch < m_extra) {                                           \
        int tc = (cch < soff) ? cch : (soff + (ng << 2) + (cch - soff));     \
        tv = x[base + tc];                                                   \
      }                                                                      \
      WAPPEND(tv, tv >= Tf)                                                  \
    }                                                                        \
    RES = cnt;                                                               \
  } while (0)

#define CAND_COUNT(TENC, RES)                                                \
  do {                                                                       \
    float Tf = dec_u(TENC);                                                  \
    unsigned cl = 0u;                                                        \
    for (unsigned i0 = 0; i0 < ncc; i0 += 64u) {                             \
      unsigned i = i0 + (unsigned)lane;                                      \
      bool have = (i < ncc);                                                 \
      int cch = have ? (int)sh_list[i] : 0;                                  \
      for (int j = 0; j < 10; ++j) {                                         \
        bool ok = have && ((j < 9) || (cch + 2304 < ng));                    \
        float4 t = make_float4(NINF, NINF, NINF, NINF);                      \
        if (ok) t = vp[cch + (j << 8)];                                      \
        cl += (t.x >= Tf) + (t.y >= Tf) + (t.z >= Tf) + (t.w >= Tf);         \
      }                                                                      \
      float tv = NINF;                                                       \
      if (have && cch < m_extra) {                                           \
        int tc = (cch < soff) ? cch : (soff + (ng << 2) + (cch - soff));     \
        tv = x[base + tc];                                                   \
      }                                                                      \
      cl += (tv >= Tf) ? 1u : 0u;                                            \
    }                                                                        \
    _Pragma("unroll") for (int off = 32; off >= 1; off >>= 1)                \
        cl += __shfl_xor(cl, off, 64);                                       \
    RES = cl;                                                                \
  } while (0)

  unsigned c;
  CAND_COMPACT(lo, c);
  unsigned compT = lo;
  unsigned E11 = lo;
  bool done = false;
  if (c < 11u) done = true;                 // only sub- -FLT_MAX pathologies
  while (!done && c > CAND_MAX) {           // bisect (rare); L2-cheap counts
    if (hi - lo <= 1u) { E11 = lo; done = true; break; }
    unsigned mid = lo + ((hi - lo) >> 1);
    unsigned cm;
    CAND_COUNT(mid, cm);
    if (cm >= 11u) { lo = mid; c = cm; } else { hi = mid; }
  }
  if (!done && lo != compT) { CAND_COMPACT(lo, c); }

  // ---- 6. exact 11th-largest via ballot binary search over sh_cand ----
  if (!done) {
    unsigned cc0 = ((unsigned)lane < c) ? sh_cand[lane] : 0u;
    unsigned cc1 = ((unsigned)lane + 64u < c) ? sh_cand[lane + 64u] : 0u;
    unsigned cc2 = ((unsigned)lane + 128u < c) ? sh_cand[lane + 128u] : 0u;
    unsigned cc3 = ((unsigned)lane + 192u < c) ? sh_cand[lane + 192u] : 0u;
    unsigned cc4 = ((unsigned)lane + 256u < c) ? sh_cand[lane + 256u] : 0u;
    unsigned cc5 = ((unsigned)lane + 320u < c) ? sh_cand[lane + 320u] : 0u;
    unsigned blo = lo, bhi = hi;
    while (bhi - blo > 1u) {                // <= ~24 iters, ballots only
      unsigned mid = blo + ((bhi - blo) >> 1);
      unsigned cnt2 = (unsigned)__popcll(__ballot(cc0 >= mid)) +
                      (unsigned)__popcll(__ballot(cc1 >= mid)) +
                      (unsigned)__popcll(__ballot(cc2 >= mid)) +
                      (unsigned)__popcll(__ballot(cc3 >= mid)) +
                      (unsigned)__popcll(__ballot(cc4 >= mid)) +
                      (unsigned)__popcll(__ballot(cc5 >= mid));
      if (cnt2 >= 11u) blo = mid; else bhi = mid;
    }
    E11 = blo;
  }

  // ---- 7. lane 0: combine whitelist partials, per-row loss ----
  if (lane == 0) {
#pragma unroll
    for (int j = 1; j < 4; ++j) {
      pmask |= sh_wpm[j];
#define CMB(l) lm_##l = fmaxf(lm_##l, sh_wlm[j][l]);
      FOR8(CMB)
#undef CMB
    }
    unsigned PR = pmask & 255u, PO = (pmask >> 8) & 255u;
    float thres = fmaxf(sigm(dec_u(E11)), 0.5f);
    float cmax = NEGF, imax = NEGF, umax = NEGF;
#define EP1(l)                                                   \
    if ((PR >> l) & 1u) {                                        \
      float ml = sigm(lm_##l);                                   \
      umax = fmaxf(umax, ml);                                    \
      if ((PO >> l) & 1u) cmax = fmaxf(cmax, ml);                \
      else imax = fmaxf(imax, ml);                               \
    }
    FOR8(EP1)
#undef EP1
    bool anyc = (PO != 0u);
    bool anyi = (PO != 255u);  // L == 8 labels always exist
    float x1 = anyc ? cmax : thres;
    float x2 = anyc ? (anyi ? fmaxf(imax, thres) : thres)
                    : ((nu > 0u) ? umax : NEGF);
    float coef = anyc ? 1.0f : 0.5f;
    float dd = x2 - x1 + 0.1f;
    float rank = ((dd > 0.0f) ? 2.0f : 1.0f) * sigm(10.0f * dd);
    partials[r] = coef * rank;
  }
}

__global__ void final_reduce(const float* __restrict__ partials,
                             float* __restrict__ out) {
  __shared__ float sh[4];
  const int tid = threadIdx.x;
  const int lane = tid & 63;
  const int wid = tid >> 6;
  float s = 0.0f;
  for (int i = tid; i < BB; i += 256) s += partials[i];
#pragma unroll
  for (int off = 32; off >= 1; off >>= 1) s += __shfl_xor(s, off, 64);
  if (lane == 0) sh[wid] = s;
  __syncthreads();
  if (tid == 0) out[0] = (sh[0] + sh[1] + sh[2] + sh[3]) * (1.0f / (float)BB);
}

extern "C" void kernel_launch(void* const* d_in, const int* in_sizes, int n_in,
                              void* d_out, int out_size, void* d_ws,
                              size_t ws_size, hipStream_t stream) {
  const float* x = (const float*)d_in[0];
  const float* y = (const float*)d_in[1];
  // d_in[2] (y_neg) is faithfully ignored — it never affects the loss.
  const unsigned char* wl = (const unsigned char*)d_in[3];
  float* out = (float*)d_out;
  unsigned* wsu = (unsigned*)d_ws;
  float* partials = (float*)((char*)d_ws + WS_PARTIALS_OFF);

  hipMemsetAsync(d_ws, 0, 16, stream);  // zero wsu[0..3]
  wl_sniff<<<64, 256, 0, stream>>>((const unsigned*)wl, wsu);
  wl_compact<<<(CC + 255) / 256, 256, 0, stream>>>(wl, wsu);
  loss_kernel<<<BB, 256, 0, stream>>>(x, y, wsu, partials);
  final_reduce<<<1, 256, 0, stream>>>(partials, out);
}